// Round 15
// baseline (163.675 us; speedup 1.0000x reference)
//
#include <hip/hip_runtime.h>
#include <math.h>

#define C 8192
#define D 1024
#define BATCH 1024
#define PM 0.95f
#define PMC 0.05f
// values pre-scaled by 8 before fp8 quant; dot comes out 64x too big.
// epilogue uses 10/64 = 0.15625 (exact in fp32).
#define INVT_SCALED 0.15625f

typedef unsigned char u8;
typedef __attribute__((ext_vector_type(16))) float f32x16;

#define GLOBAL_AS(p) ((const __attribute__((address_space(1))) void*)(p))
#define LDS_AS(p) ((__attribute__((address_space(3))) void*)(p))

// ---------------------------------------------------------------------------
// EMA + fp8 quantize, one wave per class (4 classes/block, 2048 blocks).
// Verified rounds 7-14. fp8 layout (512-B k-units for 32x32x16 fp8 MFMA):
//   element (row c, k) -> P8[(c>>5)*32768 + (k>>4)*512 + ((k>>3)&1)*256 + (c&31)*8 + (k&7)]
__global__ __launch_bounds__(256) void ema_split_kernel(const float* __restrict__ feat,
                                                        const int* __restrict__ labels,
                                                        const float* __restrict__ protos,
                                                        u8* __restrict__ P8,
                                                        float* __restrict__ rowsum,
                                                        float* __restrict__ out) {
    __shared__ int sl[BATCH];
    const int t = threadIdx.x, w = t >> 6, lane = t & 63;
    const int c = blockIdx.x * 4 + w;

    if (blockIdx.x < 32) rowsum[blockIdx.x * 256 + t] = 0.0f;
    if (blockIdx.x == 0 && t == 0) out[0] = 0.0f;

    for (int i = t; i < BATCH; i += 256) sl[i] = labels[i];
    __syncthreads();

    float4 v[4];
    #pragma unroll
    for (int s = 0; s < 4; ++s)
        v[s] = *(const float4*)(protos + (size_t)c * D + s * 256 + lane * 4);

    for (int base = 0; base < BATCH; base += 64) {
        unsigned long long mask = __ballot(sl[base + lane] == c);
        while (mask) {
            const int b = __ffsll((long long)mask) - 1;
            mask &= mask - 1;
            const int idx = base + b;
            float ss = 0.0f;
            #pragma unroll
            for (int s = 0; s < 4; ++s) {
                const float4 f = *(const float4*)(feat + (size_t)idx * D + s * 256 + lane * 4);
                v[s].x = v[s].x * PM + f.x * PMC;
                v[s].y = v[s].y * PM + f.y * PMC;
                v[s].z = v[s].z * PM + f.z * PMC;
                v[s].w = v[s].w * PM + f.w * PMC;
                ss += v[s].x * v[s].x + v[s].y * v[s].y + v[s].z * v[s].z + v[s].w * v[s].w;
            }
            #pragma unroll
            for (int off = 32; off > 0; off >>= 1) ss += __shfl_xor(ss, off);
            const float inv = 1.0f / fmaxf(sqrtf(ss), 1e-12f);
            #pragma unroll
            for (int s = 0; s < 4; ++s) {
                v[s].x *= inv; v[s].y *= inv; v[s].z *= inv; v[s].w *= inv;
            }
        }
    }

    u8* ob = P8 + (size_t)(c >> 5) * 32768 + (c & 31) * 8;
    #pragma unroll
    for (int s = 0; s < 4; ++s) {
        const int k0 = s * 256 + lane * 4;
        const size_t off = (size_t)(k0 >> 4) * 512 + ((k0 >> 3) & 1) * 256 + (k0 & 7);
        int p = __builtin_amdgcn_cvt_pk_fp8_f32(v[s].x * 8.0f, v[s].y * 8.0f, 0, false);
        p = __builtin_amdgcn_cvt_pk_fp8_f32(v[s].z * 8.0f, v[s].w * 8.0f, p, true);
        *(unsigned int*)(ob + off) = (unsigned int)p;
    }
}

// ---------------------------------------------------------------------------
// fp8 Gram, mfma_f32_32x32x16_fp8_fp8, WAVE-PRIVATE staging: each wave stages
// its own 2 A-tiles + 2 B-tiles (4 x 1 KB glds per BK=32 chunk) into a
// private 8 KB LDS region (2-deep ring) and reads only that region ->
// ZERO barriers in the K-loop. Per-wave pipeline: wait own oldest 4 glds
// (vmcnt(4): chunk kc certified; kc+1 in flight), compute kc (8 ds_read_b64
// + 8 MFMA), stage kc+2 into the buffer just freed (WAR ordered by the
// compiler's lgkmcnt(0) before the MFMAs). 4 independent free-running waves
// per SIMD hide each other's stalls; tile duplication (2x) is absorbed by
// L1 (same-CU duplicate reads). Fully unrolled -> static LDS offsets.
// 128x128 block tile, waves 2x2, wave tile 64x64 (64 AGPR acc), 32 KB LDS,
// 4 blocks/CU. Triangle cover bi<=bj (2080 blocks); diag blocks mask
// li>=lj -> rowsum == sum_neg. XCD swizzle: 260 blocks/XCD.
__global__ __launch_bounds__(256, 4) void gram8_kernel(const u8* __restrict__ P8,
                                                       float* __restrict__ rowsum) {
    __shared__ u8 lds[4][2][4096];   // [wave][ring buf][A0,A1,B0,B1 x 1 KB]
    const int t = threadIdx.x, w = t >> 6, lane = t & 63;

    // swizzled block -> (bi, bj), bi <= bj, 128-row strips
    int mm = blockIdx.x >> 3;
    const int r = blockIdx.x & 7;
    int bi = 0;
    #pragma unroll
    for (int s = 0; s < 8; ++s) {
        const int strip = (s & 1) ? ((s >> 1) * 16 + 15 - r) : ((s >> 1) * 16 + r);
        const int n = 64 - strip;
        if (mm < n) { bi = strip; break; }
        mm -= n;
    }
    const int bj = bi + mm;
    const bool diag = (bi == bj);

    const int qi = w >> 1, qj = w & 1;
    // this wave's 4 source tile-rows (A: rows of bi-strip, B: rows of bj-strip)
    const u8* gs[4];
    gs[0] = P8 + (size_t)(bi * 4 + qi * 2 + 0) * 32768 + lane * 16;
    gs[1] = P8 + (size_t)(bi * 4 + qi * 2 + 1) * 32768 + lane * 16;
    gs[2] = P8 + (size_t)(bj * 4 + qj * 2 + 0) * 32768 + lane * 16;
    gs[3] = P8 + (size_t)(bj * 4 + qj * 2 + 1) * 32768 + lane * 16;
    u8* lb = &lds[w][0][0];          // private 8 KB region

    f32x16 acc[2][2];
    #pragma unroll
    for (int a = 0; a < 2; ++a)
        #pragma unroll
        for (int b = 0; b < 2; ++b)
            #pragma unroll
            for (int e = 0; e < 16; ++e) acc[a][b][e] = 0.0f;

#define WAITV(N) asm volatile("s_waitcnt vmcnt(" #N ")" ::: "memory")

    // prologue: stage chunks 0 (buf 0) and 1 (buf 1); 8 glds outstanding
    #pragma unroll
    for (int u = 0; u < 4; ++u)
        __builtin_amdgcn_global_load_lds(GLOBAL_AS(gs[u]),
                                         LDS_AS(lb + u * 1024), 16, 0, 0);
    #pragma unroll
    for (int u = 0; u < 4; ++u)
        __builtin_amdgcn_global_load_lds(GLOBAL_AS(gs[u] + 1024),
                                         LDS_AS(lb + 4096 + u * 1024), 16, 0, 0);

    #pragma unroll
    for (int kc = 0; kc < 32; ++kc) {
        if (kc < 31) { WAITV(4); } else { WAITV(0); }   // own chunk kc certified
        const int bufo = (kc & 1) * 4096;
        #pragma unroll
        for (int kk = 0; kk < 2; ++kk) {     // 2 K-steps of K=16
            long a0 = *(const long*)(lb + bufo + 0 * 1024 + kk * 512 + lane * 8);
            long a1 = *(const long*)(lb + bufo + 1 * 1024 + kk * 512 + lane * 8);
            long b0 = *(const long*)(lb + bufo + 2 * 1024 + kk * 512 + lane * 8);
            long b1 = *(const long*)(lb + bufo + 3 * 1024 + kk * 512 + lane * 8);
            acc[0][0] = __builtin_amdgcn_mfma_f32_32x32x16_fp8_fp8(a0, b0, acc[0][0], 0, 0, 0);
            acc[0][1] = __builtin_amdgcn_mfma_f32_32x32x16_fp8_fp8(a0, b1, acc[0][1], 0, 0, 0);
            acc[1][0] = __builtin_amdgcn_mfma_f32_32x32x16_fp8_fp8(a1, b0, acc[1][0], 0, 0, 0);
            acc[1][1] = __builtin_amdgcn_mfma_f32_32x32x16_fp8_fp8(a1, b1, acc[1][1], 0, 0, 0);
        }
        if (kc < 30) {                       // stage chunk kc+2 into freed buf
            #pragma unroll
            for (int u = 0; u < 4; ++u)
                __builtin_amdgcn_global_load_lds(GLOBAL_AS(gs[u] + (size_t)(kc + 2) * 1024),
                                                 LDS_AS(lb + bufo + u * 1024), 16, 0, 0);
        }
    }

    // epilogue: exp(acc*10/64), diag-block triangle mask, row/col partials.
    // C layout (32x32): col = lane&31, row = (reg&3) + 8*(reg>>2) + 4*(lane>>5)
    __syncthreads();                         // first block-wide sync since launch
    float* rpart = (float*)&lds[0][0][0];
    float* cpart = (float*)&lds[0][0][512];
    if (t < 128) { rpart[t] = 0.0f; cpart[t] = 0.0f; }
    __syncthreads();
    const int half = lane >> 5, col = lane & 31;
    float csum[2] = {0.0f, 0.0f};
    #pragma unroll
    for (int ti = 0; ti < 2; ++ti) {
        float rs[16];
        #pragma unroll
        for (int reg = 0; reg < 16; ++reg) rs[reg] = 0.0f;
        #pragma unroll
        for (int tj = 0; tj < 2; ++tj) {
            const int lj = qj * 64 + tj * 32 + col;
            #pragma unroll
            for (int reg = 0; reg < 16; ++reg) {
                const int li = qi * 64 + ti * 32 + (reg & 3) + 8 * (reg >> 2) + 4 * half;
                float e = __expf(acc[ti][tj][reg] * INVT_SCALED);
                if (diag && li >= lj) e = 0.0f;      // bi<bj blocks: always li<lj globally
                rs[reg] += e;
                csum[tj] += e;
            }
        }
        #pragma unroll
        for (int reg = 0; reg < 16; ++reg) {
            float v = rs[reg];
            v += __shfl_xor(v, 1); v += __shfl_xor(v, 2); v += __shfl_xor(v, 4);
            v += __shfl_xor(v, 8); v += __shfl_xor(v, 16);
            if (col == 0)
                atomicAdd(&rpart[qi * 64 + ti * 32 + (reg & 3) + 8 * (reg >> 2) + 4 * half], v);
        }
    }
    #pragma unroll
    for (int tj = 0; tj < 2; ++tj) {
        float v = csum[tj];
        v += __shfl_xor(v, 32);
        if (half == 0) atomicAdd(&cpart[qj * 64 + tj * 32 + col], v);
    }
    __syncthreads();
    if (t < 128) atomicAdd(&rowsum[bi * 128 + t], rpart[t]);
    else         atomicAdd(&rowsum[bj * 128 + (t - 128)], cpart[t - 128]);
}

// ---------------------------------------------------------------------------
// rowsum == sum_neg (diag + lower triangle excluded in gram)
__global__ __launch_bounds__(256) void final2_kernel(const float* __restrict__ rowsum,
                                                     float* __restrict__ out) {
    __shared__ float red[4];
    const int t = threadIdx.x;
    const int i = blockIdx.x * 256 + t;
    float v = logf(rowsum[i] * (1.0f / (float)(C - 1)));
    #pragma unroll
    for (int off = 32; off > 0; off >>= 1) v += __shfl_down(v, off);
    if ((t & 63) == 0) red[t >> 6] = v;
    __syncthreads();
    if (t == 0)
        atomicAdd(out, (red[0] + red[1] + red[2] + red[3]) * (1.0f / (float)C));
}

// ---------------------------------------------------------------------------
extern "C" void kernel_launch(void* const* d_in, const int* in_sizes, int n_in,
                              void* d_out, int out_size, void* d_ws, size_t ws_size,
                              hipStream_t stream) {
    const float* feat = (const float*)d_in[0];
    const int* labels = (const int*)d_in[1];
    const float* protos = (const float*)d_in[2];
    float* out = (float*)d_out;
    float* rowsum = (float*)d_ws;               // 32 KB
    u8* P8 = (u8*)((char*)d_ws + 32768);        // 8 MiB packed fp8 protos

    ema_split_kernel<<<C / 4, 256, 0, stream>>>(feat, labels, protos, P8, rowsum, out);
    gram8_kernel<<<2080, 256, 0, stream>>>(P8, rowsum);
    final2_kernel<<<C / 256, 256, 0, stream>>>(rowsum, out);
}